// Round 10
// baseline (208.556 us; speedup 1.0000x reference)
//
#include <hip/hip_runtime.h>
#include <hip/hip_bf16.h>
#include <cstddef>

// Problem constants (from reference setup_inputs)
#define BB 16
#define CC 192
#define HH 64
#define WW 64
#define LL 4096   // H*W
#define DTR 12    // dt_rank
#define KK 14     // dt_rank + 2*d_state, d_state = 1
#define NSL 8     // c-slices in proj (24 channels each)

__device__ __forceinline__ float silu_f(float v) {
  return v / (1.f + __expf(-v));
}

// ---------------------------------------------------------------------------
// K1: depthwise 5x5 conv (SAME, zero pad) + bias + SiLU — LDS-free.
// One block (4 waves) per (b,c) plane; wave w owns output rows 16w..16w+15.
// (known-good, unchanged)
// ---------------------------------------------------------------------------
__global__ __launch_bounds__(256) void conv_silu_kernel(
    const float* __restrict__ x, const float* __restrict__ cw,
    const float* __restrict__ cb, float* __restrict__ xs) {
  const int bc = blockIdx.x;           // b*CC + c
  const int c = bc % CC;
  const int tid = threadIdx.x;
  const int lane = tid & 63;           // x column 0..63
  const int wv = tid >> 6;             // wave 0..3
  const int oy0 = wv * 16;             // first output row of this wave

  float w[25];
#pragma unroll
  for (int k = 0; k < 25; ++k) w[k] = cw[c * 25 + k];
  const float bias = cb[c];

  const float* xp = x + (size_t)bc * LL + lane;
  float* op = xs + (size_t)bc * LL + lane;

  // preload 20 rows (wave-uniform predication; all loads issue up front)
  float rv[20];
#pragma unroll
  for (int r = 0; r < 20; ++r) {
    const int gr = oy0 + r - 2;
    float v = 0.f;
    if ((unsigned)gr < 64u) v = xp[gr * 64];
    rv[r] = v;
  }

  float acc[5];
#pragma unroll
  for (int i = 0; i < 5; ++i) acc[i] = 0.f;

  // input row gr = oy0 + r - 2; output row y = oy0 + (r - ky).
#pragma unroll
  for (int r = 0; r < 20; ++r) {
    float v = rv[r];
    float vm2 = __shfl_up(v, 2u, 64);
    float vm1 = __shfl_up(v, 1u, 64);
    float vp1 = __shfl_down(v, 1u, 64);
    float vp2 = __shfl_down(v, 2u, 64);
    if (lane < 2) vm2 = 0.f;
    if (lane < 1) vm1 = 0.f;
    if (lane > 62) vp1 = 0.f;
    if (lane > 61) vp2 = 0.f;
    float t[5] = {vm2, vm1, v, vp1, vp2};
#pragma unroll
    for (int ky = 0; ky < 5; ++ky) {
      if (r >= ky && (r - ky) < 16) {        // static under unroll
        float s = acc[(r - ky) % 5];
#pragma unroll
        for (int kx = 0; kx < 5; ++kx) s += w[ky * 5 + kx] * t[kx];
        acc[(r - ky) % 5] = s;
      }
    }
    if (r >= 4) {                            // static under unroll
      const int yf = oy0 + r - 4;
      float a = acc[(r - 4) % 5] + bias;
      op[yf * 64] = silu_f(a);
      acc[(r - 4) % 5] = 0.f;
    }
  }
}

// ---------------------------------------------------------------------------
// K2a: partial projection. part[b][sl][k][l] = sum over this slice's
// 24 channels of x_proj_w[k][c] * xs[b][c][l]. One wave per block, no LDS,
// no atomics; xs read exactly once.  (R8 version, unchanged)
// ---------------------------------------------------------------------------
__global__ __launch_bounds__(64) void proj_part_kernel(
    const float* __restrict__ xs, const float* __restrict__ xpw,
    float* __restrict__ part) {
  const int l0 = blockIdx.x * 256;
  const int b = blockIdx.y;
  const int sl = blockIdx.z;           // slice 0..7
  const int lane = threadIdx.x;        // 0..63
  const int c0 = sl * 24;

  float4 acc[KK];
#pragma unroll
  for (int k = 0; k < KK; ++k) acc[k] = make_float4(0.f, 0.f, 0.f, 0.f);

  const float* bp = xs + ((size_t)(b * CC + c0)) * LL + l0 + lane * 4;
#pragma unroll 6
  for (int cc = 0; cc < 24; ++cc) {
    const float4 v = *(const float4*)(bp + (size_t)cc * LL);
    const int c = c0 + cc;             // wave-uniform -> scalar weight loads
#pragma unroll
    for (int k = 0; k < KK; ++k) {
      const float w = xpw[k * CC + c];
      acc[k].x += w * v.x;
      acc[k].y += w * v.y;
      acc[k].z += w * v.z;
      acc[k].w += w * v.w;
    }
  }

  float* pp = part + ((size_t)((b * NSL + sl) * KK)) * LL + l0 + lane * 4;
#pragma unroll
  for (int k = 0; k < KK; ++k)
    *(float4*)(pp + (size_t)k * LL) = acc[k];
}

// ---------------------------------------------------------------------------
// K2b: slice-reduce + dt-projection + softplus -> delta, B, C.
// Rationale: the scan was L2-BW-bound re-reading the 12 dt planes per
// (b,c) block (~740 MB of L2 loads -> structure-invariant 41.4 us).
// Precompute delta[b][c][l] HERE, where dts is block-shared:
// block (b, 256-l chunk) x 8 waves; thread reduces 8 slices x 12 planes
// into dts4[12] registers (96 float4 loads, block-shared -> L1/L2 hot);
// then wave g emits delta for channels g*24..g*24+23 (wave-uniform scalar
// weights, coalesced float4 stores). Wave 0 also emits B/C planes.
// Slice-sum order identical to the old reduce -> bit-identical dts.
// ---------------------------------------------------------------------------
__global__ __launch_bounds__(512) void reduce_delta_kernel(
    const float* __restrict__ part, const float* __restrict__ dtw,
    const float* __restrict__ dtb, float* __restrict__ delta,
    float* __restrict__ Bsp, float* __restrict__ Csp) {
  const int b = blockIdx.y;
  const int l0 = blockIdx.x * 256;
  const int tid = threadIdx.x;
  const int lane = tid & 63;
  const int g = tid >> 6;              // wave 0..7 -> channels g*24..+23
  const size_t l4 = (size_t)l0 + lane * 4;

  const float* pb = part + (size_t)b * NSL * KK * LL + l4;

  float4 dts[DTR];
#pragma unroll
  for (int r = 0; r < DTR; ++r) dts[r] = make_float4(0.f, 0.f, 0.f, 0.f);
#pragma unroll
  for (int sl = 0; sl < NSL; ++sl) {
    const float* ps = pb + (size_t)sl * KK * LL;
#pragma unroll
    for (int r = 0; r < DTR; ++r) {
      const float4 v = *(const float4*)(ps + (size_t)r * LL);
      dts[r].x += v.x; dts[r].y += v.y; dts[r].z += v.z; dts[r].w += v.w;
    }
  }

  if (g == 0) {  // B/C planes (k = 12, 13), same slice order
    float4 sb = make_float4(0.f, 0.f, 0.f, 0.f);
    float4 sc = make_float4(0.f, 0.f, 0.f, 0.f);
#pragma unroll
    for (int sl = 0; sl < NSL; ++sl) {
      const float* ps = pb + (size_t)sl * KK * LL;
      const float4 vb = *(const float4*)(ps + (size_t)12 * LL);
      const float4 vc = *(const float4*)(ps + (size_t)13 * LL);
      sb.x += vb.x; sb.y += vb.y; sb.z += vb.z; sb.w += vb.w;
      sc.x += vc.x; sc.y += vc.y; sc.z += vc.z; sc.w += vc.w;
    }
    *(float4*)(Bsp + (size_t)b * LL + l4) = sb;
    *(float4*)(Csp + (size_t)b * LL + l4) = sc;
  }

  const int c0 = g * 24;
  float* dp = delta + ((size_t)(b * CC + c0)) * LL + l4;
#pragma unroll 4
  for (int cc = 0; cc < 24; ++cc) {
    const int c = c0 + cc;             // wave-uniform -> scalar weight loads
    const float zb = dtb[c];
    float zx = zb, zy = zb, zz = zb, zw = zb;
#pragma unroll
    for (int r = 0; r < DTR; ++r) {
      const float w = dtw[c * DTR + r];
      zx += w * dts[r].x;
      zy += w * dts[r].y;
      zz += w * dts[r].z;
      zw += w * dts[r].w;
    }
    float4 d;
    d.x = (zx > 15.f) ? zx : __logf(1.f + __expf(zx));
    d.y = (zy > 15.f) ? zy : __logf(1.f + __expf(zy));
    d.z = (zz > 15.f) ? zz : __logf(1.f + __expf(zz));
    d.w = (zw > 15.f) ? zw : __logf(1.f + __expf(zw));
    *(float4*)(dp + (size_t)cc * LL) = d;
  }
}

// ---------------------------------------------------------------------------
// K3 (v4): selective scan + output, delta precomputed.
// 8 waves per (b,c); wave owns a 512-l segment = 2 chunks of 256. Per chunk
// only FOUR float4 loads (x, delta, B, C) — was 15 (12 dt planes now gone).
// Interleaved 6-step shuffle scans; 8-float LDS wave-total exchange.
// ---------------------------------------------------------------------------
__global__ __launch_bounds__(512) void scan_kernel(
    const float* __restrict__ xs, const float* __restrict__ delta,
    const float* __restrict__ Bsp, const float* __restrict__ Csp,
    const float* __restrict__ A_logs, const float* __restrict__ Ds,
    float* __restrict__ y) {
  const int bc = blockIdx.x;
  const int b = bc / CC;
  const int c = bc - b * CC;
  const int tid = threadIdx.x;
  const int lane = tid & 63;
  const int wv = tid >> 6;  // wave 0..7, owns segment [512*wv, 512*wv+511]

  const float Ac = -__expf(A_logs[c]);  // d_state = 1
  const float Dc = Ds[c];

  const float* xp = xs + (size_t)bc * LL;
  const float* ddp = delta + (size_t)bc * LL;
  const float* bpp = Bsp + (size_t)b * LL;
  const float* cpp = Csp + (size_t)b * LL;
  float* yp = y + (size_t)bc * LL;

  __shared__ float segA[8];
  __shared__ float segB[8];

  float alpha[8], beta[8];     // static indices only (full unroll)
  float aggA[2], aggB[2];

  // ---- phase 1: per-chunk lane-local scan, emit alpha/beta + aggregates ----
#pragma unroll
  for (int ck = 0; ck < 2; ++ck) {
    const int base = wv * 512 + ck * 256 + lane * 4;
    const float4 x4 = *(const float4*)(xp + base);
    const float4 d4 = *(const float4*)(ddp + base);
    const float4 B4 = *(const float4*)(bpp + base);
    const float4 C4 = *(const float4*)(cpp + base);

    float Pl = 1.f, hl = 0.f;
#pragma unroll
    for (int q = 0; q < 4; ++q) {
      const float dl = (&d4.x)[q];
      const float a = __expf(dl * Ac);
      const float be = dl * ((&B4.x)[q]) * ((&x4.x)[q]);
      hl = a * hl + be;
      Pl = Pl * a;
      alpha[ck * 4 + q] = Pl * ((&C4.x)[q]);
      beta[ck * 4 + q] = hl * ((&C4.x)[q]) + ((&x4.x)[q]) * Dc;
    }
    aggA[ck] = Pl;
    aggB[ck] = hl;
  }

  // ---- phase 2: both chunk wave-scans interleaved in lockstep ----
  float iA[2], iB[2];
#pragma unroll
  for (int ck = 0; ck < 2; ++ck) { iA[ck] = aggA[ck]; iB[ck] = aggB[ck]; }
#pragma unroll
  for (int s = 1; s < 64; s <<= 1) {
    float pA[2], pB[2];
#pragma unroll
    for (int ck = 0; ck < 2; ++ck) {
      pA[ck] = __shfl_up(iA[ck], (unsigned)s, 64);
      pB[ck] = __shfl_up(iB[ck], (unsigned)s, 64);
    }
    if (lane >= s) {
#pragma unroll
      for (int ck = 0; ck < 2; ++ck) {
        iB[ck] = iA[ck] * pB[ck] + iB[ck];
        iA[ck] = iA[ck] * pA[ck];
      }
    }
  }
  float eA[2], eB[2], tA[2], tB[2];
#pragma unroll
  for (int ck = 0; ck < 2; ++ck) {
    eA[ck] = __shfl_up(iA[ck], 1u, 64);
    eB[ck] = __shfl_up(iB[ck], 1u, 64);
    if (lane == 0) { eA[ck] = 1.f; eB[ck] = 0.f; }
    tA[ck] = __shfl(iA[ck], 63, 64);
    tB[ck] = __shfl(iB[ck], 63, 64);
  }

  // ---- phase 3: chain chunk totals; lane-entry (Pe,he) per chunk ----
  float Pe[2], he[2];
  float SP = 1.f, Sh = 0.f;   // segment state at current chunk entry
#pragma unroll
  for (int ck = 0; ck < 2; ++ck) {
    Pe[ck] = SP * eA[ck];
    he[ck] = eA[ck] * Sh + eB[ck];
    Sh = tA[ck] * Sh + tB[ck];
    SP = SP * tA[ck];
  }

  if (lane == 0) { segA[wv] = SP; segB[wv] = Sh; }
  __syncthreads();
  float carry = 0.f;
  for (int i = 0; i < wv; ++i) carry = segA[i] * carry + segB[i];

  // ---- phase 4: epilogue ----
#pragma unroll
  for (int ck = 0; ck < 2; ++ck) {
    const float G = Pe[ck] * carry + he[ck];
    const int base = wv * 512 + ck * 256 + lane * 4;
    float4 o;
    o.x = alpha[ck * 4 + 0] * G + beta[ck * 4 + 0];
    o.y = alpha[ck * 4 + 1] * G + beta[ck * 4 + 1];
    o.z = alpha[ck * 4 + 2] * G + beta[ck * 4 + 2];
    o.w = alpha[ck * 4 + 3] * G + beta[ck * 4 + 3];
    *(float4*)(yp + base) = o;
  }
}

// ---------------------------------------------------------------------------
extern "C" void kernel_launch(void* const* d_in, const int* in_sizes, int n_in,
                              void* d_out, int out_size, void* d_ws,
                              size_t ws_size, hipStream_t stream) {
  const float* x        = (const float*)d_in[0];
  const float* conv_w   = (const float*)d_in[1];
  const float* conv_b   = (const float*)d_in[2];
  const float* x_proj_w = (const float*)d_in[3];
  const float* dt_w     = (const float*)d_in[4];
  const float* dt_b     = (const float*)d_in[5];
  const float* A_logs   = (const float*)d_in[6];
  const float* Ds       = (const float*)d_in[7];
  float* out = (float*)d_out;

  char* ws = (char*)d_ws;
  const size_t plane_bytes = (size_t)BB * CC * LL * sizeof(float);     // 50.3 MB
  const size_t part_bytes  = (size_t)BB * NSL * KK * LL * sizeof(float); // 29.4 MB
  const size_t bl_bytes    = (size_t)BB * LL * sizeof(float);          // 256 KB
  float* xs    = (float*)ws;
  float* part  = (float*)(ws + plane_bytes);
  float* delta = (float*)(ws + plane_bytes + part_bytes);
  float* Bsp   = (float*)(ws + 2 * plane_bytes + part_bytes);
  float* Csp   = (float*)(ws + 2 * plane_bytes + part_bytes + bl_bytes);

  conv_silu_kernel<<<dim3(BB * CC), 256, 0, stream>>>(x, conv_w, conv_b, xs);
  proj_part_kernel<<<dim3(LL / 256, BB, NSL), 64, 0, stream>>>(
      xs, x_proj_w, part);
  reduce_delta_kernel<<<dim3(LL / 256, BB), 512, 0, stream>>>(
      part, dt_w, dt_b, delta, Bsp, Csp);
  scan_kernel<<<dim3(BB * CC), 512, 0, stream>>>(xs, delta, Bsp, Csp,
                                                 A_logs, Ds, out);
}

// Round 11
// 195.972 us; speedup vs baseline: 1.0642x; 1.0642x over previous
//
#include <hip/hip_runtime.h>
#include <hip/hip_bf16.h>
#include <cstddef>

// Problem constants (from reference setup_inputs)
#define BB 16
#define CC 192
#define HH 64
#define WW 64
#define LL 4096   // H*W
#define DTR 12    // dt_rank
#define KK 14     // dt_rank + 2*d_state, d_state = 1
#define NSL 8     // c-slices in proj (24 channels each)

__device__ __forceinline__ float silu_f(float v) {
  return v / (1.f + __expf(-v));
}

// ---------------------------------------------------------------------------
// K1: depthwise 5x5 conv (SAME, zero pad) + bias + SiLU — LDS-free.
// One block (4 waves) per (b,c) plane; wave w owns output rows 16w..16w+15.
// (known-good, unchanged)
// ---------------------------------------------------------------------------
__global__ __launch_bounds__(256) void conv_silu_kernel(
    const float* __restrict__ x, const float* __restrict__ cw,
    const float* __restrict__ cb, float* __restrict__ xs) {
  const int bc = blockIdx.x;           // b*CC + c
  const int c = bc % CC;
  const int tid = threadIdx.x;
  const int lane = tid & 63;           // x column 0..63
  const int wv = tid >> 6;             // wave 0..3
  const int oy0 = wv * 16;             // first output row of this wave

  float w[25];
#pragma unroll
  for (int k = 0; k < 25; ++k) w[k] = cw[c * 25 + k];
  const float bias = cb[c];

  const float* xp = x + (size_t)bc * LL + lane;
  float* op = xs + (size_t)bc * LL + lane;

  // preload 20 rows (wave-uniform predication; all loads issue up front)
  float rv[20];
#pragma unroll
  for (int r = 0; r < 20; ++r) {
    const int gr = oy0 + r - 2;
    float v = 0.f;
    if ((unsigned)gr < 64u) v = xp[gr * 64];
    rv[r] = v;
  }

  float acc[5];
#pragma unroll
  for (int i = 0; i < 5; ++i) acc[i] = 0.f;

  // input row gr = oy0 + r - 2; output row y = oy0 + (r - ky).
#pragma unroll
  for (int r = 0; r < 20; ++r) {
    float v = rv[r];
    float vm2 = __shfl_up(v, 2u, 64);
    float vm1 = __shfl_up(v, 1u, 64);
    float vp1 = __shfl_down(v, 1u, 64);
    float vp2 = __shfl_down(v, 2u, 64);
    if (lane < 2) vm2 = 0.f;
    if (lane < 1) vm1 = 0.f;
    if (lane > 62) vp1 = 0.f;
    if (lane > 61) vp2 = 0.f;
    float t[5] = {vm2, vm1, v, vp1, vp2};
#pragma unroll
    for (int ky = 0; ky < 5; ++ky) {
      if (r >= ky && (r - ky) < 16) {        // static under unroll
        float s = acc[(r - ky) % 5];
#pragma unroll
        for (int kx = 0; kx < 5; ++kx) s += w[ky * 5 + kx] * t[kx];
        acc[(r - ky) % 5] = s;
      }
    }
    if (r >= 4) {                            // static under unroll
      const int yf = oy0 + r - 4;
      float a = acc[(r - 4) % 5] + bias;
      op[yf * 64] = silu_f(a);
      acc[(r - 4) % 5] = 0.f;
    }
  }
}

// ---------------------------------------------------------------------------
// K2a: partial projection. part[b][sl][k][l] = sum over this slice's
// 24 channels of x_proj_w[k][c] * xs[b][c][l]. One wave per block, no LDS,
// no atomics; xs read exactly once.  (unchanged)
// ---------------------------------------------------------------------------
__global__ __launch_bounds__(64) void proj_part_kernel(
    const float* __restrict__ xs, const float* __restrict__ xpw,
    float* __restrict__ part) {
  const int l0 = blockIdx.x * 256;
  const int b = blockIdx.y;
  const int sl = blockIdx.z;           // slice 0..7
  const int lane = threadIdx.x;        // 0..63
  const int c0 = sl * 24;

  float4 acc[KK];
#pragma unroll
  for (int k = 0; k < KK; ++k) acc[k] = make_float4(0.f, 0.f, 0.f, 0.f);

  const float* bp = xs + ((size_t)(b * CC + c0)) * LL + l0 + lane * 4;
#pragma unroll 6
  for (int cc = 0; cc < 24; ++cc) {
    const float4 v = *(const float4*)(bp + (size_t)cc * LL);
    const int c = c0 + cc;             // wave-uniform -> scalar weight loads
#pragma unroll
    for (int k = 0; k < KK; ++k) {
      const float w = xpw[k * CC + c];
      acc[k].x += w * v.x;
      acc[k].y += w * v.y;
      acc[k].z += w * v.z;
      acc[k].w += w * v.w;
    }
  }

  float* pp = part + ((size_t)((b * NSL + sl) * KK)) * LL + l0 + lane * 4;
#pragma unroll
  for (int k = 0; k < KK; ++k)
    *(float4*)(pp + (size_t)k * LL) = acc[k];
}

// ---------------------------------------------------------------------------
// K2b (v2): slice-reduce + dt-projection + softplus -> delta, B, C.
// OCCUPANCY FIX vs R10 (52 us @ 17% occupancy, 17% VALU, 256 blocks =
// 8 waves/CU, VGPR 128): grid (32 l-chunks, 16 b, 2 channel-halves) =
// 1024 blocks x 8 waves = 32 waves/CU requested; thread owns 2 l's
// (float2 -> dts in 24 VGPR); wave g emits 12 channels. Part dt-planes
// read twice (once per half) — +25 MB from the L3-hot part buffer.
// Slice-sum order identical -> bit-identical dts/delta.
// ---------------------------------------------------------------------------
__global__ __launch_bounds__(512) void reduce_delta_kernel(
    const float* __restrict__ part, const float* __restrict__ dtw,
    const float* __restrict__ dtb, float* __restrict__ delta,
    float* __restrict__ Bsp, float* __restrict__ Csp) {
  const int b = blockIdx.y;
  const int l0 = blockIdx.x * 128;
  const int half = blockIdx.z;         // 0,1 -> channels half*96 .. +95
  const int tid = threadIdx.x;
  const int lane = tid & 63;
  const int g = tid >> 6;              // wave 0..7 -> 12 channels each
  const size_t l2 = (size_t)l0 + lane * 2;

  const float* pb = part + (size_t)b * NSL * KK * LL + l2;

  float2 dts[DTR];
#pragma unroll
  for (int r = 0; r < DTR; ++r) dts[r] = make_float2(0.f, 0.f);
#pragma unroll
  for (int sl = 0; sl < NSL; ++sl) {
    const float* ps = pb + (size_t)sl * KK * LL;
#pragma unroll
    for (int r = 0; r < DTR; ++r) {
      const float2 v = *(const float2*)(ps + (size_t)r * LL);
      dts[r].x += v.x;
      dts[r].y += v.y;
    }
  }

  if (half == 0 && g == 0) {  // B/C planes (k = 12, 13), same slice order
    float2 sb = make_float2(0.f, 0.f);
    float2 sc = make_float2(0.f, 0.f);
#pragma unroll
    for (int sl = 0; sl < NSL; ++sl) {
      const float* ps = pb + (size_t)sl * KK * LL;
      const float2 vb = *(const float2*)(ps + (size_t)12 * LL);
      const float2 vc = *(const float2*)(ps + (size_t)13 * LL);
      sb.x += vb.x; sb.y += vb.y;
      sc.x += vc.x; sc.y += vc.y;
    }
    *(float2*)(Bsp + (size_t)b * LL + l2) = sb;
    *(float2*)(Csp + (size_t)b * LL + l2) = sc;
  }

  const int c0 = half * 96 + g * 12;
  float* dp = delta + ((size_t)(b * CC + c0)) * LL + l2;
#pragma unroll 4
  for (int cc = 0; cc < 12; ++cc) {
    const int c = c0 + cc;             // wave-uniform -> scalar weight loads
    const float zb = dtb[c];
    float zx = zb, zy = zb;
#pragma unroll
    for (int r = 0; r < DTR; ++r) {
      const float w = dtw[c * DTR + r];
      zx += w * dts[r].x;
      zy += w * dts[r].y;
    }
    float2 d;
    d.x = (zx > 15.f) ? zx : __logf(1.f + __expf(zx));
    d.y = (zy > 15.f) ? zy : __logf(1.f + __expf(zy));
    *(float2*)(dp + (size_t)cc * LL) = d;
  }
}

// ---------------------------------------------------------------------------
// K3 (v4): selective scan + output, delta precomputed.
// 8 waves per (b,c); wave owns a 512-l segment = 2 chunks of 256. Per chunk
// only FOUR float4 loads (x, delta, B, C). Interleaved 6-step shuffle scans;
// 8-float LDS wave-total exchange.  (unchanged)
// ---------------------------------------------------------------------------
__global__ __launch_bounds__(512) void scan_kernel(
    const float* __restrict__ xs, const float* __restrict__ delta,
    const float* __restrict__ Bsp, const float* __restrict__ Csp,
    const float* __restrict__ A_logs, const float* __restrict__ Ds,
    float* __restrict__ y) {
  const int bc = blockIdx.x;
  const int b = bc / CC;
  const int c = bc - b * CC;
  const int tid = threadIdx.x;
  const int lane = tid & 63;
  const int wv = tid >> 6;  // wave 0..7, owns segment [512*wv, 512*wv+511]

  const float Ac = -__expf(A_logs[c]);  // d_state = 1
  const float Dc = Ds[c];

  const float* xp = xs + (size_t)bc * LL;
  const float* ddp = delta + (size_t)bc * LL;
  const float* bpp = Bsp + (size_t)b * LL;
  const float* cpp = Csp + (size_t)b * LL;
  float* yp = y + (size_t)bc * LL;

  __shared__ float segA[8];
  __shared__ float segB[8];

  float alpha[8], beta[8];     // static indices only (full unroll)
  float aggA[2], aggB[2];

  // ---- phase 1: per-chunk lane-local scan, emit alpha/beta + aggregates ----
#pragma unroll
  for (int ck = 0; ck < 2; ++ck) {
    const int base = wv * 512 + ck * 256 + lane * 4;
    const float4 x4 = *(const float4*)(xp + base);
    const float4 d4 = *(const float4*)(ddp + base);
    const float4 B4 = *(const float4*)(bpp + base);
    const float4 C4 = *(const float4*)(cpp + base);

    float Pl = 1.f, hl = 0.f;
#pragma unroll
    for (int q = 0; q < 4; ++q) {
      const float dl = (&d4.x)[q];
      const float a = __expf(dl * Ac);
      const float be = dl * ((&B4.x)[q]) * ((&x4.x)[q]);
      hl = a * hl + be;
      Pl = Pl * a;
      alpha[ck * 4 + q] = Pl * ((&C4.x)[q]);
      beta[ck * 4 + q] = hl * ((&C4.x)[q]) + ((&x4.x)[q]) * Dc;
    }
    aggA[ck] = Pl;
    aggB[ck] = hl;
  }

  // ---- phase 2: both chunk wave-scans interleaved in lockstep ----
  float iA[2], iB[2];
#pragma unroll
  for (int ck = 0; ck < 2; ++ck) { iA[ck] = aggA[ck]; iB[ck] = aggB[ck]; }
#pragma unroll
  for (int s = 1; s < 64; s <<= 1) {
    float pA[2], pB[2];
#pragma unroll
    for (int ck = 0; ck < 2; ++ck) {
      pA[ck] = __shfl_up(iA[ck], (unsigned)s, 64);
      pB[ck] = __shfl_up(iB[ck], (unsigned)s, 64);
    }
    if (lane >= s) {
#pragma unroll
      for (int ck = 0; ck < 2; ++ck) {
        iB[ck] = iA[ck] * pB[ck] + iB[ck];
        iA[ck] = iA[ck] * pA[ck];
      }
    }
  }
  float eA[2], eB[2], tA[2], tB[2];
#pragma unroll
  for (int ck = 0; ck < 2; ++ck) {
    eA[ck] = __shfl_up(iA[ck], 1u, 64);
    eB[ck] = __shfl_up(iB[ck], 1u, 64);
    if (lane == 0) { eA[ck] = 1.f; eB[ck] = 0.f; }
    tA[ck] = __shfl(iA[ck], 63, 64);
    tB[ck] = __shfl(iB[ck], 63, 64);
  }

  // ---- phase 3: chain chunk totals; lane-entry (Pe,he) per chunk ----
  float Pe[2], he[2];
  float SP = 1.f, Sh = 0.f;   // segment state at current chunk entry
#pragma unroll
  for (int ck = 0; ck < 2; ++ck) {
    Pe[ck] = SP * eA[ck];
    he[ck] = eA[ck] * Sh + eB[ck];
    Sh = tA[ck] * Sh + tB[ck];
    SP = SP * tA[ck];
  }

  if (lane == 0) { segA[wv] = SP; segB[wv] = Sh; }
  __syncthreads();
  float carry = 0.f;
  for (int i = 0; i < wv; ++i) carry = segA[i] * carry + segB[i];

  // ---- phase 4: epilogue ----
#pragma unroll
  for (int ck = 0; ck < 2; ++ck) {
    const float G = Pe[ck] * carry + he[ck];
    const int base = wv * 512 + ck * 256 + lane * 4;
    float4 o;
    o.x = alpha[ck * 4 + 0] * G + beta[ck * 4 + 0];
    o.y = alpha[ck * 4 + 1] * G + beta[ck * 4 + 1];
    o.z = alpha[ck * 4 + 2] * G + beta[ck * 4 + 2];
    o.w = alpha[ck * 4 + 3] * G + beta[ck * 4 + 3];
    *(float4*)(yp + base) = o;
  }
}

// ---------------------------------------------------------------------------
extern "C" void kernel_launch(void* const* d_in, const int* in_sizes, int n_in,
                              void* d_out, int out_size, void* d_ws,
                              size_t ws_size, hipStream_t stream) {
  const float* x        = (const float*)d_in[0];
  const float* conv_w   = (const float*)d_in[1];
  const float* conv_b   = (const float*)d_in[2];
  const float* x_proj_w = (const float*)d_in[3];
  const float* dt_w     = (const float*)d_in[4];
  const float* dt_b     = (const float*)d_in[5];
  const float* A_logs   = (const float*)d_in[6];
  const float* Ds       = (const float*)d_in[7];
  float* out = (float*)d_out;

  char* ws = (char*)d_ws;
  const size_t plane_bytes = (size_t)BB * CC * LL * sizeof(float);     // 50.3 MB
  const size_t part_bytes  = (size_t)BB * NSL * KK * LL * sizeof(float); // 29.4 MB
  const size_t bl_bytes    = (size_t)BB * LL * sizeof(float);          // 256 KB
  float* xs    = (float*)ws;
  float* part  = (float*)(ws + plane_bytes);
  float* delta = (float*)(ws + plane_bytes + part_bytes);
  float* Bsp   = (float*)(ws + 2 * plane_bytes + part_bytes);
  float* Csp   = (float*)(ws + 2 * plane_bytes + part_bytes + bl_bytes);

  conv_silu_kernel<<<dim3(BB * CC), 256, 0, stream>>>(x, conv_w, conv_b, xs);
  proj_part_kernel<<<dim3(LL / 256, BB, NSL), 64, 0, stream>>>(
      xs, x_proj_w, part);
  reduce_delta_kernel<<<dim3(LL / 128, BB, 2), 512, 0, stream>>>(
      part, dt_w, dt_b, delta, Bsp, Csp);
  scan_kernel<<<dim3(BB * CC), 512, 0, stream>>>(xs, delta, Bsp, Csp,
                                                 A_logs, Ds, out);
}

// Round 12
// 180.994 us; speedup vs baseline: 1.1523x; 1.0828x over previous
//
#include <hip/hip_runtime.h>
#include <hip/hip_bf16.h>
#include <cstddef>

// Problem constants (from reference setup_inputs)
#define BB 16
#define CC 192
#define HH 64
#define WW 64
#define LL 4096   // H*W
#define DTR 12    // dt_rank
#define KK 14     // dt_rank + 2*d_state, d_state = 1
#define NSL 8     // c-slices in proj (24 channels each)

__device__ __forceinline__ float silu_f(float v) {
  return v / (1.f + __expf(-v));
}

// ---------------------------------------------------------------------------
// K1: depthwise 5x5 conv (SAME, zero pad) + bias + SiLU — LDS-free.
// One block (4 waves) per (b,c) plane; wave w owns output rows 16w..16w+15.
// (known-good, unchanged)
// ---------------------------------------------------------------------------
__global__ __launch_bounds__(256) void conv_silu_kernel(
    const float* __restrict__ x, const float* __restrict__ cw,
    const float* __restrict__ cb, float* __restrict__ xs) {
  const int bc = blockIdx.x;           // b*CC + c
  const int c = bc % CC;
  const int tid = threadIdx.x;
  const int lane = tid & 63;           // x column 0..63
  const int wv = tid >> 6;             // wave 0..3
  const int oy0 = wv * 16;             // first output row of this wave

  float w[25];
#pragma unroll
  for (int k = 0; k < 25; ++k) w[k] = cw[c * 25 + k];
  const float bias = cb[c];

  const float* xp = x + (size_t)bc * LL + lane;
  float* op = xs + (size_t)bc * LL + lane;

  // preload 20 rows (wave-uniform predication; all loads issue up front)
  float rv[20];
#pragma unroll
  for (int r = 0; r < 20; ++r) {
    const int gr = oy0 + r - 2;
    float v = 0.f;
    if ((unsigned)gr < 64u) v = xp[gr * 64];
    rv[r] = v;
  }

  float acc[5];
#pragma unroll
  for (int i = 0; i < 5; ++i) acc[i] = 0.f;

  // input row gr = oy0 + r - 2; output row y = oy0 + (r - ky).
#pragma unroll
  for (int r = 0; r < 20; ++r) {
    float v = rv[r];
    float vm2 = __shfl_up(v, 2u, 64);
    float vm1 = __shfl_up(v, 1u, 64);
    float vp1 = __shfl_down(v, 1u, 64);
    float vp2 = __shfl_down(v, 2u, 64);
    if (lane < 2) vm2 = 0.f;
    if (lane < 1) vm1 = 0.f;
    if (lane > 62) vp1 = 0.f;
    if (lane > 61) vp2 = 0.f;
    float t[5] = {vm2, vm1, v, vp1, vp2};
#pragma unroll
    for (int ky = 0; ky < 5; ++ky) {
      if (r >= ky && (r - ky) < 16) {        // static under unroll
        float s = acc[(r - ky) % 5];
#pragma unroll
        for (int kx = 0; kx < 5; ++kx) s += w[ky * 5 + kx] * t[kx];
        acc[(r - ky) % 5] = s;
      }
    }
    if (r >= 4) {                            // static under unroll
      const int yf = oy0 + r - 4;
      float a = acc[(r - 4) % 5] + bias;
      op[yf * 64] = silu_f(a);
      acc[(r - 4) % 5] = 0.f;
    }
  }
}

// ---------------------------------------------------------------------------
// K2a: partial projection. part[b][sl][k][l] = sum over this slice's
// 24 channels of x_proj_w[k][c] * xs[b][c][l]. One wave per block, no LDS,
// no atomics; xs read exactly once.  (unchanged)
// ---------------------------------------------------------------------------
__global__ __launch_bounds__(64) void proj_part_kernel(
    const float* __restrict__ xs, const float* __restrict__ xpw,
    float* __restrict__ part) {
  const int l0 = blockIdx.x * 256;
  const int b = blockIdx.y;
  const int sl = blockIdx.z;           // slice 0..7
  const int lane = threadIdx.x;        // 0..63
  const int c0 = sl * 24;

  float4 acc[KK];
#pragma unroll
  for (int k = 0; k < KK; ++k) acc[k] = make_float4(0.f, 0.f, 0.f, 0.f);

  const float* bp = xs + ((size_t)(b * CC + c0)) * LL + l0 + lane * 4;
#pragma unroll 6
  for (int cc = 0; cc < 24; ++cc) {
    const float4 v = *(const float4*)(bp + (size_t)cc * LL);
    const int c = c0 + cc;             // wave-uniform -> scalar weight loads
#pragma unroll
    for (int k = 0; k < KK; ++k) {
      const float w = xpw[k * CC + c];
      acc[k].x += w * v.x;
      acc[k].y += w * v.y;
      acc[k].z += w * v.z;
      acc[k].w += w * v.w;
    }
  }

  float* pp = part + ((size_t)((b * NSL + sl) * KK)) * LL + l0 + lane * 4;
#pragma unroll
  for (int k = 0; k < KK; ++k)
    *(float4*)(pp + (size_t)k * LL) = acc[k];
}

// ---------------------------------------------------------------------------
// K2b (v3): slice-reduce + dt-projection + softplus via LDS staging.
// R10/R11 post-mortem: per-thread private gathers of 96 small 16KB-strided
// values from part serialize at L2 latency (48-52 us, VALU 17-24%, two
// tilings within 7%). FIX the PATTERN: block (b, 128-l chunk) stages its
// whole [8][14][128] part slab (56 KB LDS, every byte read once grid-wide)
// with coalesced float4 streams (7/thread, independent), then the
// slice-reduce is 96 stride-1 LDS reads (2-way bank alias = free) and each
// thread emits 48 channels (wave-uniform scalar weights). VGPR ~50 (no
// global loads kept live). MI355X LDS 160KB/CU -> 2 blocks/CU.
// Slice-sum + FMA order identical -> bit-identical delta/B/C.
// ---------------------------------------------------------------------------
__global__ __launch_bounds__(512) void reduce_delta_kernel(
    const float* __restrict__ part, const float* __restrict__ dtw,
    const float* __restrict__ dtb, float* __restrict__ delta,
    float* __restrict__ Bsp, float* __restrict__ Csp) {
  const int b = blockIdx.y;
  const int l0 = blockIdx.x * 128;
  const int tid = threadIdx.x;

  __shared__ float lds[NSL * KK * 128];   // 56 KB

  // ---- stage: 7 coalesced float4 per thread, linear over [sl][k][l] ----
  const float* pb = part + (size_t)b * NSL * KK * LL + l0;
#pragma unroll
  for (int i = 0; i < 7; ++i) {
    const int fi = (i * 512 + tid) * 4;      // float index, multiple of 4
    const int l = fi & 127;                  // 128 % 4 == 0: row-safe
    const int row = fi >> 7;                 // sl*KK + k, 0..111
    const float4 v = *(const float4*)(pb + (size_t)row * LL + l);
    *(float4*)&lds[fi] = v;
  }
  __syncthreads();

  // ---- compute: thread = (l = tid&127, cg = tid>>7 -> 48 channels) ----
  const int l = tid & 127;
  const int cg = tid >> 7;                   // 0..3 (wave-uniform)

  float dts[DTR];
#pragma unroll
  for (int r = 0; r < DTR; ++r) {
    float s = 0.f;
#pragma unroll
    for (int sl = 0; sl < NSL; ++sl) s += lds[(sl * KK + r) * 128 + l];
    dts[r] = s;
  }

  if (cg == 0) {  // B/C planes (k = 12, 13), same slice order
    float sb = 0.f, sc = 0.f;
#pragma unroll
    for (int sl = 0; sl < NSL; ++sl) {
      sb += lds[(sl * KK + 12) * 128 + l];
      sc += lds[(sl * KK + 13) * 128 + l];
    }
    Bsp[(size_t)b * LL + l0 + l] = sb;
    Csp[(size_t)b * LL + l0 + l] = sc;
  }

  const int c0 = cg * 48;
  float* dp = delta + ((size_t)(b * CC + c0)) * LL + l0 + l;
#pragma unroll 4
  for (int cc = 0; cc < 48; ++cc) {
    const int c = c0 + cc;                   // wave-uniform -> scalar weights
    float z = dtb[c];
#pragma unroll
    for (int r = 0; r < DTR; ++r) z += dtw[c * DTR + r] * dts[r];
    dp[(size_t)cc * LL] = (z > 15.f) ? z : __logf(1.f + __expf(z));
  }
}

// ---------------------------------------------------------------------------
// K3 (v4): selective scan + output, delta precomputed.
// 8 waves per (b,c); wave owns a 512-l segment = 2 chunks of 256. Per chunk
// only FOUR float4 loads (x, delta, B, C). Interleaved 6-step shuffle scans;
// 8-float LDS wave-total exchange.  (unchanged)
// ---------------------------------------------------------------------------
__global__ __launch_bounds__(512) void scan_kernel(
    const float* __restrict__ xs, const float* __restrict__ delta,
    const float* __restrict__ Bsp, const float* __restrict__ Csp,
    const float* __restrict__ A_logs, const float* __restrict__ Ds,
    float* __restrict__ y) {
  const int bc = blockIdx.x;
  const int b = bc / CC;
  const int c = bc - b * CC;
  const int tid = threadIdx.x;
  const int lane = tid & 63;
  const int wv = tid >> 6;  // wave 0..7, owns segment [512*wv, 512*wv+511]

  const float Ac = -__expf(A_logs[c]);  // d_state = 1
  const float Dc = Ds[c];

  const float* xp = xs + (size_t)bc * LL;
  const float* ddp = delta + (size_t)bc * LL;
  const float* bpp = Bsp + (size_t)b * LL;
  const float* cpp = Csp + (size_t)b * LL;
  float* yp = y + (size_t)bc * LL;

  __shared__ float segA[8];
  __shared__ float segB[8];

  float alpha[8], beta[8];     // static indices only (full unroll)
  float aggA[2], aggB[2];

  // ---- phase 1: per-chunk lane-local scan, emit alpha/beta + aggregates ----
#pragma unroll
  for (int ck = 0; ck < 2; ++ck) {
    const int base = wv * 512 + ck * 256 + lane * 4;
    const float4 x4 = *(const float4*)(xp + base);
    const float4 d4 = *(const float4*)(ddp + base);
    const float4 B4 = *(const float4*)(bpp + base);
    const float4 C4 = *(const float4*)(cpp + base);

    float Pl = 1.f, hl = 0.f;
#pragma unroll
    for (int q = 0; q < 4; ++q) {
      const float dl = (&d4.x)[q];
      const float a = __expf(dl * Ac);
      const float be = dl * ((&B4.x)[q]) * ((&x4.x)[q]);
      hl = a * hl + be;
      Pl = Pl * a;
      alpha[ck * 4 + q] = Pl * ((&C4.x)[q]);
      beta[ck * 4 + q] = hl * ((&C4.x)[q]) + ((&x4.x)[q]) * Dc;
    }
    aggA[ck] = Pl;
    aggB[ck] = hl;
  }

  // ---- phase 2: both chunk wave-scans interleaved in lockstep ----
  float iA[2], iB[2];
#pragma unroll
  for (int ck = 0; ck < 2; ++ck) { iA[ck] = aggA[ck]; iB[ck] = aggB[ck]; }
#pragma unroll
  for (int s = 1; s < 64; s <<= 1) {
    float pA[2], pB[2];
#pragma unroll
    for (int ck = 0; ck < 2; ++ck) {
      pA[ck] = __shfl_up(iA[ck], (unsigned)s, 64);
      pB[ck] = __shfl_up(iB[ck], (unsigned)s, 64);
    }
    if (lane >= s) {
#pragma unroll
      for (int ck = 0; ck < 2; ++ck) {
        iB[ck] = iA[ck] * pB[ck] + iB[ck];
        iA[ck] = iA[ck] * pA[ck];
      }
    }
  }
  float eA[2], eB[2], tA[2], tB[2];
#pragma unroll
  for (int ck = 0; ck < 2; ++ck) {
    eA[ck] = __shfl_up(iA[ck], 1u, 64);
    eB[ck] = __shfl_up(iB[ck], 1u, 64);
    if (lane == 0) { eA[ck] = 1.f; eB[ck] = 0.f; }
    tA[ck] = __shfl(iA[ck], 63, 64);
    tB[ck] = __shfl(iB[ck], 63, 64);
  }

  // ---- phase 3: chain chunk totals; lane-entry (Pe,he) per chunk ----
  float Pe[2], he[2];
  float SP = 1.f, Sh = 0.f;   // segment state at current chunk entry
#pragma unroll
  for (int ck = 0; ck < 2; ++ck) {
    Pe[ck] = SP * eA[ck];
    he[ck] = eA[ck] * Sh + eB[ck];
    Sh = tA[ck] * Sh + tB[ck];
    SP = SP * tA[ck];
  }

  if (lane == 0) { segA[wv] = SP; segB[wv] = Sh; }
  __syncthreads();
  float carry = 0.f;
  for (int i = 0; i < wv; ++i) carry = segA[i] * carry + segB[i];

  // ---- phase 4: epilogue ----
#pragma unroll
  for (int ck = 0; ck < 2; ++ck) {
    const float G = Pe[ck] * carry + he[ck];
    const int base = wv * 512 + ck * 256 + lane * 4;
    float4 o;
    o.x = alpha[ck * 4 + 0] * G + beta[ck * 4 + 0];
    o.y = alpha[ck * 4 + 1] * G + beta[ck * 4 + 1];
    o.z = alpha[ck * 4 + 2] * G + beta[ck * 4 + 2];
    o.w = alpha[ck * 4 + 3] * G + beta[ck * 4 + 3];
    *(float4*)(yp + base) = o;
  }
}

// ---------------------------------------------------------------------------
extern "C" void kernel_launch(void* const* d_in, const int* in_sizes, int n_in,
                              void* d_out, int out_size, void* d_ws,
                              size_t ws_size, hipStream_t stream) {
  const float* x        = (const float*)d_in[0];
  const float* conv_w   = (const float*)d_in[1];
  const float* conv_b   = (const float*)d_in[2];
  const float* x_proj_w = (const float*)d_in[3];
  const float* dt_w     = (const float*)d_in[4];
  const float* dt_b     = (const float*)d_in[5];
  const float* A_logs   = (const float*)d_in[6];
  const float* Ds       = (const float*)d_in[7];
  float* out = (float*)d_out;

  char* ws = (char*)d_ws;
  const size_t plane_bytes = (size_t)BB * CC * LL * sizeof(float);     // 50.3 MB
  const size_t part_bytes  = (size_t)BB * NSL * KK * LL * sizeof(float); // 29.4 MB
  const size_t bl_bytes    = (size_t)BB * LL * sizeof(float);          // 256 KB
  float* xs    = (float*)ws;
  float* part  = (float*)(ws + plane_bytes);
  float* delta = (float*)(ws + plane_bytes + part_bytes);
  float* Bsp   = (float*)(ws + 2 * plane_bytes + part_bytes);
  float* Csp   = (float*)(ws + 2 * plane_bytes + part_bytes + bl_bytes);

  conv_silu_kernel<<<dim3(BB * CC), 256, 0, stream>>>(x, conv_w, conv_b, xs);
  proj_part_kernel<<<dim3(LL / 256, BB, NSL), 64, 0, stream>>>(
      xs, x_proj_w, part);
  reduce_delta_kernel<<<dim3(LL / 128, BB), 512, 0, stream>>>(
      part, dt_w, dt_b, delta, Bsp, Csp);
  scan_kernel<<<dim3(BB * CC), 512, 0, stream>>>(xs, delta, Bsp, Csp,
                                                 A_logs, Ds, out);
}